// Round 5
// baseline (2982.402 us; speedup 1.0000x reference)
//
#include <hip/hip_runtime.h>

using u16    = unsigned short;
using u64_t  = unsigned long long;
using short4v = __attribute__((ext_vector_type(4))) short;
using short8 = __attribute__((ext_vector_type(8))) short;
using f32x4  = __attribute__((ext_vector_type(4))) float;

#define T_STEPS 512
#define BATCH   128
#define HDIM    512
#define EDIM    256
#define NWG     256
#define WGS     256
// packed h: [slot][cg(64)][row(128)][8 cols] bf16 -> 64*128*8 u16 per slot (128KB)
#define HPITCH  65536

__device__ __forceinline__ u16 f2bf(float f) {
  unsigned u = __float_as_uint(f);
  u += 0x7FFFu + ((u >> 16) & 1u);   // RNE
  return (u16)(u >> 16);
}
__device__ __forceinline__ float bf2f(u16 h) {
  return __uint_as_float(((unsigned)h) << 16);
}
__device__ __forceinline__ float sigm(float x) { return 1.0f / (1.0f + __expf(-x)); }
__device__ __forceinline__ float ftanh(float x) { return 1.0f - 2.0f / (__expf(2.0f * x) + 1.0f); }

// ---- coherent (agent-scope) accessors: LLC-coherent, bypass L1/L2 ----
__device__ __forceinline__ u64_t cl8(const u16* p) {
  return __hip_atomic_load((const u64_t*)p, __ATOMIC_RELAXED, __HIP_MEMORY_SCOPE_AGENT);
}
__device__ __forceinline__ void cstore2(u16* p, u16 v) {
  __hip_atomic_store(p, v, __ATOMIC_RELAXED, __HIP_MEMORY_SCOPE_AGENT);
}
__device__ __forceinline__ void cstore4(int* p, int v) {
  __hip_atomic_store(p, v, __ATOMIC_RELAXED, __HIP_MEMORY_SCOPE_AGENT);
}
__device__ __forceinline__ int ld4(const int* p) {
  return __hip_atomic_load(p, __ATOMIC_RELAXED, __HIP_MEMORY_SCOPE_AGENT);
}
__device__ __forceinline__ int addag(int* p, int v) {
  return __hip_atomic_fetch_add(p, v, __ATOMIC_RELAXED, __HIP_MEMORY_SCOPE_AGENT);
}
__device__ __forceinline__ short8 mk8(u64_t lo, u64_t hi) {
  short4v a = __builtin_bit_cast(short4v, lo);
  short4v b = __builtin_bit_cast(short4v, hi);
  return __builtin_shufflevector(a, b, 0, 1, 2, 3, 4, 5, 6, 7);
}

// ---------------- x -> bf16 prep ----------------
__global__ void cvt_bf16_kernel(const float* __restrict__ src, u16* __restrict__ dst, int n4) {
  int i = blockIdx.x * blockDim.x + threadIdx.x;
  if (i >= n4) return;
  float4 v = ((const float4*)src)[i];
  uint2 o;
  o.x = (unsigned)f2bf(v.x) | ((unsigned)f2bf(v.y) << 16);
  o.y = (unsigned)f2bf(v.z) | ((unsigned)f2bf(v.w) << 16);
  ((uint2*)dst)[i] = o;
}

// ---------------- sync area layout (first 32KB of ws, zeroed per launch) ----------------
//  4096 + gid*256 + nc*4 : per-WG stamps (4 groups x 64 WGs x 4B; group = 4 lines)
//  8192 : fallback grid barrier cnt (8 x 256B); root @10240; rel @10368
// Stamps are monotone epochs (= completed steps); no re-arm.

// ---------------- full grid barrier (hist=0 fallback only) ----------------
__device__ __forceinline__ void grid_barrier(int* cnt, int* root, int* rel,
                                             int it, int tid, int bid) {
  __syncthreads();
  if (tid == 0) {
    int* mycnt = cnt + (bid >> 5) * 64;   // 8 sub-counters, 256B apart
    int old = addag(mycnt, 1);
    if (old == 32 * (it + 1) - 1) {
      int r = addag(root, 1);
      if (r == 8 * (it + 1) - 1) cstore4(rel, it + 1);
    }
    while (ld4(rel) < it + 1) __builtin_amdgcn_s_sleep(1);
  }
  __syncthreads();
}

// ---------------- persistent 2-layer LSTM, direct-stamp sync ----------------
// hist mode: h[t] at a UNIQUE slot -> plain cached consumer loads (L2 broadcast;
// verified rounds 2-3). Sync = per-WG monotone stamps, no tree/release:
//   publish: all-wave vmcnt(0) drain -> __syncthreads -> tid0 plain agent store
//   wait:    wave 0 does one 64-lane agent load of the group's 64 stamps + __all
//            (L1 also checks paired L0 group >= t+1 in the same loop), then
//            __syncthreads releases the other waves.
// 3 LLC hops/step (stamp land, observe, h-load) vs round-3's 5 (sub RMW, root
// RMW, release store, observe, h-load). Only wave 0 polls (256 waves, <=512B)
// -> ~30x less poll traffic than the round-1 failure mode.
__global__ void __launch_bounds__(WGS, 1) lstm_kernel(
    const float* __restrict__ wih0, const float* __restrict__ whh0,
    const float* __restrict__ bih0, const float* __restrict__ bhh0,
    const float* __restrict__ wih1, const float* __restrict__ whh1,
    const float* __restrict__ bih1, const float* __restrict__ bhh1,
    const float* __restrict__ wfc,  const float* __restrict__ bfc,
    const u16* __restrict__ xbf, u16* __restrict__ h0buf, u16* __restrict__ h1buf,
    float* __restrict__ out, int* syncp, int hist)
{
  extern __shared__ u16 smem[];
  u16* Ws_in  = smem;            // [K_in/8][32][8]
  u16* Ws_rec = smem + 16384;    // [64][32][8]

  const int tid    = threadIdx.x;
  const int bid    = blockIdx.x;
  const int layer  = bid >> 7;          // 0..1
  const int lb     = bid & 127;
  const int mhalf  = lb & 1;            // batch half
  const int nc     = lb >> 1;           // 0..63 -> 8 h-cols each
  const int jbase  = nc * 8;
  const int w      = tid >> 6;          // wave 0..3 -> 16 batch rows each
  const int lane   = tid & 63;
  const int l15    = lane & 15;
  const int q      = lane >> 4;
  const int wmbase = mhalf * 64 + w * 16;
  const int gid    = layer * 2 + mhalf; // sync group (64 WGs)

  char* sb = (char*)syncp;

  const int K_in = layer ? HDIM : EDIM;
  const float* Wih = layer ? wih1 : wih0;
  const float* Whh = layer ? whh1 : whh0;
  const float* Bih = layer ? bih1 : bih0;
  const float* Bhh = layer ? bhh1 : bhh0;

  // ---- one-time: stage weight slices to LDS as bf16, layout [k/8][n][8] ----
  for (int p = tid; p < 32 * (K_in / 8); p += WGS) {
    int c = p >> 5, n = p & 31;
    int grow = (n >> 3) * HDIM + jbase + (n & 7);     // gate*512 + col
    const float* s = Wih + (size_t)grow * K_in + c * 8;
    u16* d = Ws_in + p * 8;
    #pragma unroll
    for (int e = 0; e < 8; ++e) d[e] = f2bf(s[e]);
  }
  for (int p = tid; p < 32 * (HDIM / 8); p += WGS) {
    int c = p >> 5, n = p & 31;
    int grow = (n >> 3) * HDIM + jbase + (n & 7);
    const float* s = Whh + (size_t)grow * HDIM + c * 8;
    u16* d = Ws_rec + p * 8;
    #pragma unroll
    for (int e = 0; e < 8; ++e) d[e] = f2bf(s[e]);
  }

  // per-lane biases for column cc = l15&7 (lanes n and n+8 duplicate the same column)
  const int cc = l15 & 7;
  const float bi_i = Bih[0*HDIM + jbase + cc] + Bhh[0*HDIM + jbase + cc];
  const float bi_f = Bih[1*HDIM + jbase + cc] + Bhh[1*HDIM + jbase + cc];
  const float bi_g = Bih[2*HDIM + jbase + cc] + Bhh[2*HDIM + jbase + cc];
  const float bi_o = Bih[3*HDIM + jbase + cc] + Bhh[3*HDIM + jbase + cc];

  __syncthreads();

  float cst[4] = {0.f, 0.f, 0.f, 0.f};   // c-state: 4 rows (q*4+r) x col cc
  u16* ownbuf = layer ? h1buf : h0buf;
  const int arow = wmbase + l15;
  // packed per-(q,row) consumer base offset: ((q*128)+arow)*8 ; per kk add 4096
  const size_t cbase = ((size_t)q * 128 + arow) * 8;

  // MFMA helper: 4 accumulator chains (A/B by kk parity) to cover MFMA dep latency.
  auto MM2 = [&](short8 a, const u16* Ws, int kk, f32x4& A0, f32x4& A1) {
    const u16* bb = Ws + (kk * 4 + q) * 256 + l15 * 8;
    short8 b0 = *(const short8*)bb;
    short8 b1 = *(const short8*)(bb + 128);
    A0 = __builtin_amdgcn_mfma_f32_16x16x32_bf16(a, b0, A0, 0, 0, 0);
    A1 = __builtin_amdgcn_mfma_f32_16x16x32_bf16(a, b1, A1, 0, 0, 0);
  };

  if (hist) {
    // ================= direct-stamp main loop =================
    int* my_stamp = (int*)(sb + 4096 + (size_t)gid * 256 + (size_t)nc * 4);
    const int* own_st = (const int*)(sb + 4096 + (size_t)gid * 256);     // lane-indexed
    const int* l0_st  = (const int*)(sb + 4096 + (size_t)mhalf * 256);   // paired L0 group

    for (int t = 0; t < T_STEPS; ++t) {
      // x prefetch (layer 0) BEFORE the wait: HBM/L2 latency hides under poll
      short8 xfr[8];
      if (layer == 0) {
        const u16* xb = xbf + ((size_t)arow * T_STEPS + t) * EDIM + q * 8;
        #pragma unroll
        for (int kk = 0; kk < 8; ++kk) xfr[kk] = *(const short8*)(xb + kk * 32);
      }

      // ---- WAIT: wave 0 polls 64 stamps lane-parallel; other waves at s_barrier ----
      if (w == 0) {
        if (layer == 0) {
          if (t > 0) {
            for (;;) { int s = ld4(own_st + lane); if (__all(s >= t)) break; }
          }
        } else {
          for (;;) {
            int s  = ld4(own_st + lane);
            int s0 = ld4(l0_st + lane);
            if (__all((s >= t) && (s0 >= t + 1))) break;
          }
        }
      }
      __syncthreads();

      // ---- BATCHED LOAD PHASE (plain cached: unique slot addresses) ----
      short8 ifr[16];
      short8 rfr[16];
      if (layer == 1) {
        const u16* ab = h0buf + (size_t)t * HPITCH + cbase;
        #pragma unroll
        for (int kk = 0; kk < 16; ++kk) ifr[kk] = *(const short8*)(ab + kk * 4096);
      }
      if (t > 0) {
        const u16* rb = ownbuf + (size_t)(t - 1) * HPITCH + cbase;
        #pragma unroll
        for (int kk = 0; kk < 16; ++kk) rfr[kk] = *(const short8*)(rb + kk * 4096);
      }

      // ---- MFMA PHASE ----
      f32x4 a0A = {0,0,0,0}, a1A = {0,0,0,0}, a0B = {0,0,0,0}, a1B = {0,0,0,0};
      if (layer == 0) {
        #pragma unroll
        for (int kk = 0; kk < 8; ++kk)
          MM2(xfr[kk], Ws_in, kk, (kk & 1) ? a0B : a0A, (kk & 1) ? a1B : a1A);
      } else {
        #pragma unroll
        for (int kk = 0; kk < 16; ++kk)
          MM2(ifr[kk], Ws_in, kk, (kk & 1) ? a0B : a0A, (kk & 1) ? a1B : a1A);
      }
      if (t > 0) {
        #pragma unroll
        for (int kk = 0; kk < 16; ++kk)
          MM2(rfr[kk], Ws_rec, kk, (kk & 1) ? a0B : a0A, (kk & 1) ? a1B : a1A);
      }
      f32x4 acc0 = a0A + a0B;
      f32x4 acc1 = a1A + a1B;

      // ---- gate epilogue ----
      u16* hw = ownbuf + (size_t)t * HPITCH + (size_t)nc * 1024;  // [cg][row][8]
      const bool low = (l15 < 8);
      #pragma unroll
      for (int r = 0; r < 4; ++r) {
        float a0 = acc0[r], a1 = acc1[r];
        float p0 = __shfl_xor(a0, 8);
        float p1 = __shfl_xor(a1, 8);
        float iv = low ? a0 : p0;
        float fv = low ? p0 : a0;
        float gv = low ? a1 : p1;
        float ov = low ? p1 : a1;
        iv = sigm(iv + bi_i);
        fv = sigm(fv + bi_f);
        gv = ftanh(gv + bi_g);
        ov = sigm(ov + bi_o);
        float cn = fv * cst[r] + iv * gv;
        cst[r] = cn;
        float hv = ov * ftanh(cn);
        if (low) cstore2(&hw[(size_t)(wmbase + q * 4 + r) * 8 + cc], f2bf(hv));
      }

      // ---- PUBLISH: per-wave drain -> WG barrier -> tid0 plain stamp store ----
      asm volatile("s_waitcnt vmcnt(0)" ::: "memory");
      __syncthreads();
      if (tid == 0) cstore4(my_stamp, t + 1);
    }

    // ---- FC epilogue: wait both L1 groups done, then out = sigmoid(h2.wfc+bfc) ----
    if (bid == NWG - 1) {
      const int* g2 = (const int*)(sb + 4096 + (size_t)2 * 256);
      const int* g3 = (const int*)(sb + 4096 + (size_t)3 * 256);
      if (w == 0) {
        for (;;) {
          int a = ld4(g2 + lane);
          int b = ld4(g3 + lane);
          if (__all((a >= T_STEPS) && (b >= T_STEPS))) break;
        }
      }
      __syncthreads();
      __builtin_amdgcn_fence(__ATOMIC_ACQUIRE, "agent");
      const int b = tid >> 1, half = tid & 1;
      const u16* hp = h1buf + (size_t)(T_STEPS - 1) * HPITCH;
      const float* wf = wfc + half * 256;
      float s = 0.f;
      for (int cg = 0; cg < 32; ++cg) {
        const u16* p = hp + ((size_t)(half * 32 + cg) * 128 + b) * 8;
        #pragma unroll
        for (int e = 0; e < 8; ++e) s += bf2f(p[e]) * wf[cg * 8 + e];
      }
      s += __shfl_xor(s, 1);
      if (half == 0) out[b] = sigm(s + bfc[0]);
    }
    return;
  }

  // ================= hist=0 fallback: rigid full-grid barrier, 2-slot ring =================
  int* f_cnt  = (int*)(sb + 8192);
  int* f_root = (int*)(sb + 10240);
  int* f_rel  = (int*)(sb + 10368);
  for (int it = 0; it <= T_STEPS; ++it) {
    const int t = layer ? (it - 1) : it;
    if (t >= 0 && t < T_STEPS) {
      short8 ifr[16];
      short8 rfr[16];
      short8 xfr[8];
      if (layer == 1) {
        const u16* ab = h0buf + (size_t)(t & 1) * HPITCH + cbase;
        #pragma unroll
        for (int kk = 0; kk < 16; ++kk)
          ifr[kk] = mk8(cl8(ab + kk * 4096), cl8(ab + kk * 4096 + 4));
      }
      if (t > 0) {
        const u16* rb = ownbuf + (size_t)((t - 1) & 1) * HPITCH + cbase;
        #pragma unroll
        for (int kk = 0; kk < 16; ++kk)
          rfr[kk] = mk8(cl8(rb + kk * 4096), cl8(rb + kk * 4096 + 4));
      }
      if (layer == 0) {
        const u16* xb = xbf + ((size_t)arow * T_STEPS + t) * EDIM + q * 8;
        #pragma unroll
        for (int kk = 0; kk < 8; ++kk) xfr[kk] = *(const short8*)(xb + kk * 32);
      }

      f32x4 a0A = {0,0,0,0}, a1A = {0,0,0,0}, a0B = {0,0,0,0}, a1B = {0,0,0,0};
      if (layer == 0) {
        #pragma unroll
        for (int kk = 0; kk < 8; ++kk)
          MM2(xfr[kk], Ws_in, kk, (kk & 1) ? a0B : a0A, (kk & 1) ? a1B : a1A);
      } else {
        #pragma unroll
        for (int kk = 0; kk < 16; ++kk)
          MM2(ifr[kk], Ws_in, kk, (kk & 1) ? a0B : a0A, (kk & 1) ? a1B : a1A);
      }
      if (t > 0) {
        #pragma unroll
        for (int kk = 0; kk < 16; ++kk)
          MM2(rfr[kk], Ws_rec, kk, (kk & 1) ? a0B : a0A, (kk & 1) ? a1B : a1A);
      }
      f32x4 acc0 = a0A + a0B;
      f32x4 acc1 = a1A + a1B;

      u16* hw = ownbuf + (size_t)(t & 1) * HPITCH + (size_t)nc * 1024;
      const bool low = (l15 < 8);
      #pragma unroll
      for (int r = 0; r < 4; ++r) {
        float a0 = acc0[r], a1 = acc1[r];
        float p0 = __shfl_xor(a0, 8);
        float p1 = __shfl_xor(a1, 8);
        float iv = low ? a0 : p0;
        float fv = low ? p0 : a0;
        float gv = low ? a1 : p1;
        float ov = low ? p1 : a1;
        iv = sigm(iv + bi_i);
        fv = sigm(fv + bi_f);
        gv = ftanh(gv + bi_g);
        ov = sigm(ov + bi_o);
        float cn = fv * cst[r] + iv * gv;
        cst[r] = cn;
        float hv = ov * ftanh(cn);
        if (low) cstore2(&hw[(size_t)(wmbase + q * 4 + r) * 8 + cc], f2bf(hv));
      }
    }
    grid_barrier(f_cnt, f_root, f_rel, it, tid, bid);
  }
  if (bid == NWG - 1) {
    __builtin_amdgcn_fence(__ATOMIC_ACQUIRE, "agent");
    const int b = tid >> 1, half = tid & 1;
    const u16* hp = h1buf + (size_t)1 * HPITCH;
    const float* wf = wfc + half * 256;
    float s = 0.f;
    for (int cg = 0; cg < 32; ++cg) {
      const u16* p = hp + ((size_t)(half * 32 + cg) * 128 + b) * 8;
      #pragma unroll
      for (int e = 0; e < 8; ++e) s += bf2f(p[e]) * wf[cg * 8 + e];
    }
    s += __shfl_xor(s, 1);
    if (half == 0) out[b] = sigm(s + bfc[0]);
  }
}

extern "C" void kernel_launch(void* const* d_in, const int* in_sizes, int n_in,
                              void* d_out, int out_size, void* d_ws, size_t ws_size,
                              hipStream_t stream) {
  (void)in_sizes; (void)n_in; (void)out_size;
  const float* x    = (const float*)d_in[0];
  const float* wih0 = (const float*)d_in[1];
  const float* whh0 = (const float*)d_in[2];
  const float* bih0 = (const float*)d_in[3];
  const float* bhh0 = (const float*)d_in[4];
  const float* wih1 = (const float*)d_in[5];
  const float* whh1 = (const float*)d_in[6];
  const float* bih1 = (const float*)d_in[7];
  const float* bhh1 = (const float*)d_in[8];
  const float* wfc  = (const float*)d_in[9];
  const float* bfc  = (const float*)d_in[10];
  float* outp = (float*)d_out;

  char* ws = (char*)d_ws;
  int*  syncp = (int*)ws;                                      // 32KB sync state
  u16*  xbf   = (u16*)(ws + 32768);                            // 128*512*256 bf16 = 32 MiB
  u16*  h0    = (u16*)(ws + 32768 + 33554432);

  // hist mode: h[t] at a unique slot (512 x 128KB per layer) -> plain cached loads
  // + direct-stamp sync. Else: 2-slot ring + full grid barrier.
  const size_t need_hist = 32768ull + 33554432ull + 2ull * T_STEPS * HPITCH * sizeof(u16);
  const int hist = (ws_size >= need_hist) ? 1 : 0;
  const size_t slots = hist ? T_STEPS : 2;
  u16* h1 = h0 + slots * HPITCH;

  hipMemsetAsync(d_ws, 0, 32768, stream);                      // zero sync state

  const int n4 = (BATCH * T_STEPS * EDIM) / 4;                 // 4,194,304
  cvt_bf16_kernel<<<n4 / 256, 256, 0, stream>>>(x, xbf, n4);

  hipFuncSetAttribute((const void*)lstm_kernel,
                      hipFuncAttributeMaxDynamicSharedMemorySize, 65536);

  void* args[] = { (void*)&wih0, (void*)&whh0, (void*)&bih0, (void*)&bhh0,
                   (void*)&wih1, (void*)&whh1, (void*)&bih1, (void*)&bhh1,
                   (void*)&wfc,  (void*)&bfc,
                   (void*)&xbf,  (void*)&h0,   (void*)&h1,
                   (void*)&outp, (void*)&syncp, (void*)&hist };
  hipLaunchCooperativeKernel((void*)lstm_kernel, dim3(NWG), dim3(WGS),
                             args, 65536, stream);
}

// Round 7
// 2557.884 us; speedup vs baseline: 1.1660x; 1.1660x over previous
//
#include <hip/hip_runtime.h>

using u16    = unsigned short;
using u64_t  = unsigned long long;
using short4v = __attribute__((ext_vector_type(4))) short;
using short8 = __attribute__((ext_vector_type(8))) short;
using f32x4  = __attribute__((ext_vector_type(4))) float;

#define T_STEPS 512
#define BATCH   128
#define HDIM    512
#define EDIM    256
#define NWG     256
#define WGS     256
// packed h: [slot][cg(64)][row(128)][8 cols] bf16 -> 64*128*8 u16 per slot (128KB)
#define HPITCH  65536

__device__ __forceinline__ u16 f2bf(float f) {
  unsigned u = __float_as_uint(f);
  u += 0x7FFFu + ((u >> 16) & 1u);   // RNE
  return (u16)(u >> 16);
}
__device__ __forceinline__ float bf2f(u16 h) {
  return __uint_as_float(((unsigned)h) << 16);
}
__device__ __forceinline__ float sigm(float x) { return 1.0f / (1.0f + __expf(-x)); }
__device__ __forceinline__ float ftanh(float x) { return 1.0f - 2.0f / (__expf(2.0f * x) + 1.0f); }

// ---- coherent (agent-scope) accessors: LLC-coherent, bypass L1/L2 ----
__device__ __forceinline__ u64_t cl8(const u16* p) {
  return __hip_atomic_load((const u64_t*)p, __ATOMIC_RELAXED, __HIP_MEMORY_SCOPE_AGENT);
}
__device__ __forceinline__ void cstore2(u16* p, u16 v) {
  __hip_atomic_store(p, v, __ATOMIC_RELAXED, __HIP_MEMORY_SCOPE_AGENT);
}
__device__ __forceinline__ void cstore4(int* p, int v) {
  __hip_atomic_store(p, v, __ATOMIC_RELAXED, __HIP_MEMORY_SCOPE_AGENT);
}
__device__ __forceinline__ int ld4(const int* p) {
  return __hip_atomic_load(p, __ATOMIC_RELAXED, __HIP_MEMORY_SCOPE_AGENT);
}
__device__ __forceinline__ int addag(int* p, int v) {
  return __hip_atomic_fetch_add(p, v, __ATOMIC_RELAXED, __HIP_MEMORY_SCOPE_AGENT);
}
__device__ __forceinline__ short8 mk8(u64_t lo, u64_t hi) {
  short4v a = __builtin_bit_cast(short4v, lo);
  short4v b = __builtin_bit_cast(short4v, hi);
  return __builtin_shufflevector(a, b, 0, 1, 2, 3, 4, 5, 6, 7);
}

// ---------------- x -> bf16 prep ----------------
__global__ void cvt_bf16_kernel(const float* __restrict__ src, u16* __restrict__ dst, int n4) {
  int i = blockIdx.x * blockDim.x + threadIdx.x;
  if (i >= n4) return;
  float4 v = ((const float4*)src)[i];
  uint2 o;
  o.x = (unsigned)f2bf(v.x) | ((unsigned)f2bf(v.y) << 16);
  o.y = (unsigned)f2bf(v.z) | ((unsigned)f2bf(v.w) << 16);
  ((uint2*)dst)[i] = o;
}

// ---------------- sync area (first 32KB of ws, zeroed per launch) ----------------
//     0..8191  : sub-counters       gid*2048 + sub*256     (4 groups x 8 subs)
//  8192..10239 : fallback grid barrier cnt (8 x 256B)
// 10240 / 10496: fallback root / release word
// 12288..28671 : sub-release lines  12288 + ((gid*8+sub)*4 + rep)*128
//                (4 replicas per sub; writer = the sub winner; <=32 pollers/line)
// Values are monotone epochs (= completed steps); no re-arm.

__device__ __forceinline__ void grid_barrier(int* cnt, int* root, int* rel,
                                             int it, int tid, int bid) {
  __syncthreads();
  if (tid == 0) {
    int* mycnt = cnt + (bid >> 5) * 64;   // 8 sub-counters, 256B apart
    int old = addag(mycnt, 1);
    if (old == 32 * (it + 1) - 1) {
      int r = addag(root, 1);
      if (r == 8 * (it + 1) - 1) cstore4(rel, it + 1);
    }
    while (ld4(rel) < it + 1) __builtin_amdgcn_s_sleep(1);
  }
  __syncthreads();
}

// ---------------- persistent 2-layer LSTM, flat sub-release sync ----------------
// hist mode (R3-verified core + two strict simplifications):
//  (1) publish: sub RMW (8 WGs/sub, as R3) -> the winner stores epoch t+1 into
//      its sub's 4 replica release lines. No root RMW, no central release:
//      one fewer serial LLC hop on the producer->consumer chain.
//  (2) wait: wave 0 polls all 8 subs lane-parallel (lanes 0-7 own group; for
//      layer 1, lanes 8-15 poll the paired L0 group at >= t+1 FIRST, so the
//      input-GEMM (h0[t] load + 16 MM2) runs while own-group producers finish).
// h exchange: unique-slot plain cached loads (R2/R3-verified). Epilogue,
// staging, fallback: byte-identical to R3.
__global__ void __launch_bounds__(WGS, 1) lstm_kernel(
    const float* __restrict__ wih0, const float* __restrict__ whh0,
    const float* __restrict__ bih0, const float* __restrict__ bhh0,
    const float* __restrict__ wih1, const float* __restrict__ whh1,
    const float* __restrict__ bih1, const float* __restrict__ bhh1,
    const float* __restrict__ wfc,  const float* __restrict__ bfc,
    const u16* __restrict__ xbf, u16* __restrict__ h0buf, u16* __restrict__ h1buf,
    float* __restrict__ out, int* syncp, int hist)
{
  extern __shared__ u16 smem[];
  u16* Ws_in  = smem;            // [K_in/8][32][8]
  u16* Ws_rec = smem + 16384;    // [64][32][8]

  const int tid    = threadIdx.x;
  const int bid    = blockIdx.x;
  const int layer  = bid >> 7;          // 0..1
  const int lb     = bid & 127;
  const int mhalf  = lb & 1;            // batch half
  const int nc     = lb >> 1;           // 0..63 -> 8 h-cols each
  const int jbase  = nc * 8;
  const int w      = tid >> 6;          // wave 0..3 -> 16 batch rows each
  const int lane   = tid & 63;
  const int l15    = lane & 15;
  const int q      = lane >> 4;
  const int wmbase = mhalf * 64 + w * 16;
  const int gid    = layer * 2 + mhalf; // sync group (64 WGs)

  char* sb = (char*)syncp;

  const int K_in = layer ? HDIM : EDIM;
  const float* Wih = layer ? wih1 : wih0;
  const float* Whh = layer ? whh1 : whh0;
  const float* Bih = layer ? bih1 : bih0;
  const float* Bhh = layer ? bhh1 : bhh0;

  // ---- one-time: stage weight slices to LDS as bf16, layout [k/8][n][8] ----
  for (int p = tid; p < 32 * (K_in / 8); p += WGS) {
    int c = p >> 5, n = p & 31;
    int grow = (n >> 3) * HDIM + jbase + (n & 7);     // gate*512 + col
    const float* s = Wih + (size_t)grow * K_in + c * 8;
    u16* d = Ws_in + p * 8;
    #pragma unroll
    for (int e = 0; e < 8; ++e) d[e] = f2bf(s[e]);
  }
  for (int p = tid; p < 32 * (HDIM / 8); p += WGS) {
    int c = p >> 5, n = p & 31;
    int grow = (n >> 3) * HDIM + jbase + (n & 7);
    const float* s = Whh + (size_t)grow * HDIM + c * 8;
    u16* d = Ws_rec + p * 8;
    #pragma unroll
    for (int e = 0; e < 8; ++e) d[e] = f2bf(s[e]);
  }

  // per-lane biases for column cc = l15&7 (lanes n and n+8 duplicate the same column)
  const int cc = l15 & 7;
  const float bi_i = Bih[0*HDIM + jbase + cc] + Bhh[0*HDIM + jbase + cc];
  const float bi_f = Bih[1*HDIM + jbase + cc] + Bhh[1*HDIM + jbase + cc];
  const float bi_g = Bih[2*HDIM + jbase + cc] + Bhh[2*HDIM + jbase + cc];
  const float bi_o = Bih[3*HDIM + jbase + cc] + Bhh[3*HDIM + jbase + cc];

  __syncthreads();

  float cst[4] = {0.f, 0.f, 0.f, 0.f};   // c-state: 4 rows (q*4+r) x col cc
  u16* ownbuf = layer ? h1buf : h0buf;
  const int arow = wmbase + l15;
  // packed per-(q,row) consumer base offset: ((q*128)+arow)*8 ; per kk add 4096
  const size_t cbase = ((size_t)q * 128 + arow) * 8;

  // MFMA helper: 4 accumulator chains (A/B by kk parity) to cover MFMA dep latency.
  auto MM2 = [&](short8 a, const u16* Ws, int kk, f32x4& A0, f32x4& A1) {
    const u16* bb = Ws + (kk * 4 + q) * 256 + l15 * 8;
    short8 b0 = *(const short8*)bb;
    short8 b1 = *(const short8*)(bb + 128);
    A0 = __builtin_amdgcn_mfma_f32_16x16x32_bf16(a, b0, A0, 0, 0, 0);
    A1 = __builtin_amdgcn_mfma_f32_16x16x32_bf16(a, b1, A1, 0, 0, 0);
  };

  if (hist) {
    // ================= flat sub-release main loop =================
    char* rel2 = sb + 12288;
    int* sub_cnt = (int*)(sb + (size_t)gid * 2048 + (size_t)(nc >> 3) * 256);
    const int myrep = nc & 3;
    // wave-0 per-lane poll lines: lanes 0-7 own group's subs; lanes 8-15 paired L0 subs
    const int* pl_own = (const int*)(rel2 + (((size_t)gid * 8 + (lane & 7)) * 4 + myrep) * 128);
    const int* pl_l0  = (const int*)(rel2 + (((size_t)mhalf * 8 + (lane & 7)) * 4 + myrep) * 128);
    int* my_rel = (int*)(rel2 + ((size_t)gid * 8 + (nc >> 3)) * 4 * 128);

    for (int t = 0; t < T_STEPS; ++t) {
      f32x4 a0A = {0,0,0,0}, a1A = {0,0,0,0}, a0B = {0,0,0,0}, a1B = {0,0,0,0};

      // ---- input-GEMM half (dependency-free / cross-layer only) ----
      if (layer == 0) {
        short8 xfr[8];
        const u16* xb = xbf + ((size_t)arow * T_STEPS + t) * EDIM + q * 8;
        #pragma unroll
        for (int kk = 0; kk < 8; ++kk) xfr[kk] = *(const short8*)(xb + kk * 32);
        #pragma unroll
        for (int kk = 0; kk < 8; ++kk)
          MM2(xfr[kk], Ws_in, kk, (kk & 1) ? a0B : a0A, (kk & 1) ? a1B : a1A);
      } else {
        // wait h0[t] (L0 free-runs ahead; usually already satisfied)
        if (w == 0) {
          for (;;) {
            bool ok = true;
            if (lane >= 8 && lane < 16) ok = (ld4(pl_l0) >= t + 1);
            if (__all(ok)) break;
          }
        }
        __syncthreads();
        short8 ifr[16];
        const u16* ab = h0buf + (size_t)t * HPITCH + cbase;
        #pragma unroll
        for (int kk = 0; kk < 16; ++kk) ifr[kk] = *(const short8*)(ab + kk * 4096);
        #pragma unroll
        for (int kk = 0; kk < 16; ++kk)
          MM2(ifr[kk], Ws_in, kk, (kk & 1) ? a0B : a0A, (kk & 1) ? a1B : a1A);
      }

      // ---- recurrent half (own-group dependency) ----
      if (t > 0) {
        if (w == 0) {
          for (;;) {
            bool ok = true;
            if (lane < 8) ok = (ld4(pl_own) >= t);
            if (__all(ok)) break;
          }
        }
        __syncthreads();
        short8 rfr[16];
        const u16* rb = ownbuf + (size_t)(t - 1) * HPITCH + cbase;
        #pragma unroll
        for (int kk = 0; kk < 16; ++kk) rfr[kk] = *(const short8*)(rb + kk * 4096);
        #pragma unroll
        for (int kk = 0; kk < 16; ++kk)
          MM2(rfr[kk], Ws_rec, kk, (kk & 1) ? a0B : a0A, (kk & 1) ? a1B : a1A);
      }

      f32x4 acc0 = a0A + a0B;
      f32x4 acc1 = a1A + a1B;

      // ---- gate epilogue (R3-identical) ----
      u16* hw = ownbuf + (size_t)t * HPITCH + (size_t)nc * 1024;  // [cg][row][8]
      const bool low = (l15 < 8);
      #pragma unroll
      for (int r = 0; r < 4; ++r) {
        float a0 = acc0[r], a1 = acc1[r];
        float p0 = __shfl_xor(a0, 8);
        float p1 = __shfl_xor(a1, 8);
        float iv = low ? a0 : p0;
        float fv = low ? p0 : a0;
        float gv = low ? a1 : p1;
        float ov = low ? p1 : a1;
        iv = sigm(iv + bi_i);
        fv = sigm(fv + bi_f);
        gv = ftanh(gv + bi_g);
        ov = sigm(ov + bi_o);
        float cn = fv * cst[r] + iv * gv;
        cst[r] = cn;
        float hv = ov * ftanh(cn);
        if (low) cstore2(&hw[(size_t)(wmbase + q * 4 + r) * 8 + cc], f2bf(hv));
      }

      // ---- PUBLISH: __syncthreads drains vmcnt per wave (R3-proven); sub winner
      // stores epoch to its 4 replica lines (store issues after the RMW's return
      // value resolves the branch -> ordered after all 8 producers' drains) ----
      __syncthreads();
      if (tid == 0) {
        int old = addag(sub_cnt, 1);
        if (old == 8 * (t + 1) - 1) {
          #pragma unroll
          for (int rp = 0; rp < 4; ++rp)
            cstore4((int*)((char*)my_rel + (size_t)rp * 128), t + 1);
        }
      }
    }

    // ---- FC epilogue: wait all subs of both L1 groups, then out = sigmoid(h2.wfc+bfc) ----
    if (bid == NWG - 1) {
      if (w == 0) {
        for (;;) {
          bool ok = true;
          if (lane < 8)
            ok = (ld4((const int*)(rel2 + ((size_t)2 * 8 + lane) * 4 * 128)) >= T_STEPS);
          else if (lane < 16)
            ok = (ld4((const int*)(rel2 + ((size_t)3 * 8 + (lane - 8)) * 4 * 128)) >= T_STEPS);
          if (__all(ok)) break;
        }
      }
      __syncthreads();
      __builtin_amdgcn_fence(__ATOMIC_ACQUIRE, "agent");
      const int b = tid >> 1, half = tid & 1;
      const u16* hp = h1buf + (size_t)(T_STEPS - 1) * HPITCH;
      const float* wf = wfc + half * 256;
      float s = 0.f;
      for (int cg = 0; cg < 32; ++cg) {
        const u16* p = hp + ((size_t)(half * 32 + cg) * 128 + b) * 8;
        #pragma unroll
        for (int e = 0; e < 8; ++e) s += bf2f(p[e]) * wf[cg * 8 + e];
      }
      s += __shfl_xor(s, 1);
      if (half == 0) out[b] = sigm(s + bfc[0]);
    }
    return;
  }

  // ================= hist=0 fallback: rigid full-grid barrier, 2-slot ring =================
  int* f_cnt  = (int*)(sb + 8192);
  int* f_root = (int*)(sb + 10240);
  int* f_rel  = (int*)(sb + 10496);
  for (int it = 0; it <= T_STEPS; ++it) {
    const int t = layer ? (it - 1) : it;
    if (t >= 0 && t < T_STEPS) {
      short8 ifr[16];
      short8 rfr[16];
      short8 xfr[8];
      if (layer == 1) {
        const u16* ab = h0buf + (size_t)(t & 1) * HPITCH + cbase;
        #pragma unroll
        for (int kk = 0; kk < 16; ++kk)
          ifr[kk] = mk8(cl8(ab + kk * 4096), cl8(ab + kk * 4096 + 4));
      }
      if (t > 0) {
        const u16* rb = ownbuf + (size_t)((t - 1) & 1) * HPITCH + cbase;
        #pragma unroll
        for (int kk = 0; kk < 16; ++kk)
          rfr[kk] = mk8(cl8(rb + kk * 4096), cl8(rb + kk * 4096 + 4));
      }
      if (layer == 0) {
        const u16* xb = xbf + ((size_t)arow * T_STEPS + t) * EDIM + q * 8;
        #pragma unroll
        for (int kk = 0; kk < 8; ++kk) xfr[kk] = *(const short8*)(xb + kk * 32);
      }

      f32x4 a0A = {0,0,0,0}, a1A = {0,0,0,0}, a0B = {0,0,0,0}, a1B = {0,0,0,0};
      if (layer == 0) {
        #pragma unroll
        for (int kk = 0; kk < 8; ++kk)
          MM2(xfr[kk], Ws_in, kk, (kk & 1) ? a0B : a0A, (kk & 1) ? a1B : a1A);
      } else {
        #pragma unroll
        for (int kk = 0; kk < 16; ++kk)
          MM2(ifr[kk], Ws_in, kk, (kk & 1) ? a0B : a0A, (kk & 1) ? a1B : a1A);
      }
      if (t > 0) {
        #pragma unroll
        for (int kk = 0; kk < 16; ++kk)
          MM2(rfr[kk], Ws_rec, kk, (kk & 1) ? a0B : a0A, (kk & 1) ? a1B : a1A);
      }
      f32x4 acc0 = a0A + a0B;
      f32x4 acc1 = a1A + a1B;

      u16* hw = ownbuf + (size_t)(t & 1) * HPITCH + (size_t)nc * 1024;
      const bool low = (l15 < 8);
      #pragma unroll
      for (int r = 0; r < 4; ++r) {
        float a0 = acc0[r], a1 = acc1[r];
        float p0 = __shfl_xor(a0, 8);
        float p1 = __shfl_xor(a1, 8);
        float iv = low ? a0 : p0;
        float fv = low ? p0 : a0;
        float gv = low ? a1 : p1;
        float ov = low ? p1 : a1;
        iv = sigm(iv + bi_i);
        fv = sigm(fv + bi_f);
        gv = ftanh(gv + bi_g);
        ov = sigm(ov + bi_o);
        float cn = fv * cst[r] + iv * gv;
        cst[r] = cn;
        float hv = ov * ftanh(cn);
        if (low) cstore2(&hw[(size_t)(wmbase + q * 4 + r) * 8 + cc], f2bf(hv));
      }
    }
    grid_barrier(f_cnt, f_root, f_rel, it, tid, bid);
  }
  if (bid == NWG - 1) {
    __builtin_amdgcn_fence(__ATOMIC_ACQUIRE, "agent");
    const int b = tid >> 1, half = tid & 1;
    const u16* hp = h1buf + (size_t)1 * HPITCH;
    const float* wf = wfc + half * 256;
    float s = 0.f;
    for (int cg = 0; cg < 32; ++cg) {
      const u16* p = hp + ((size_t)(half * 32 + cg) * 128 + b) * 8;
      #pragma unroll
      for (int e = 0; e < 8; ++e) s += bf2f(p[e]) * wf[cg * 8 + e];
    }
    s += __shfl_xor(s, 1);
    if (half == 0) out[b] = sigm(s + bfc[0]);
  }
}

extern "C" void kernel_launch(void* const* d_in, const int* in_sizes, int n_in,
                              void* d_out, int out_size, void* d_ws, size_t ws_size,
                              hipStream_t stream) {
  (void)in_sizes; (void)n_in; (void)out_size;
  const float* x    = (const float*)d_in[0];
  const float* wih0 = (const float*)d_in[1];
  const float* whh0 = (const float*)d_in[2];
  const float* bih0 = (const float*)d_in[3];
  const float* bhh0 = (const float*)d_in[4];
  const float* wih1 = (const float*)d_in[5];
  const float* whh1 = (const float*)d_in[6];
  const float* bih1 = (const float*)d_in[7];
  const float* bhh1 = (const float*)d_in[8];
  const float* wfc  = (const float*)d_in[9];
  const float* bfc  = (const float*)d_in[10];
  float* outp = (float*)d_out;

  char* ws = (char*)d_ws;
  int*  syncp = (int*)ws;                                      // 32KB sync state
  u16*  xbf   = (u16*)(ws + 32768);                            // 128*512*256 bf16 = 32 MiB
  u16*  h0    = (u16*)(ws + 32768 + 33554432);

  // hist mode: h[t] at a unique slot (512 x 128KB per layer) -> plain cached loads
  // + flat sub-release sync. Else: 2-slot ring + full grid barrier.
  const size_t need_hist = 32768ull + 33554432ull + 2ull * T_STEPS * HPITCH * sizeof(u16);
  const int hist = (ws_size >= need_hist) ? 1 : 0;
  const size_t slots = hist ? T_STEPS : 2;
  u16* h1 = h0 + slots * HPITCH;

  hipMemsetAsync(d_ws, 0, 32768, stream);                      // zero sync state

  const int n4 = (BATCH * T_STEPS * EDIM) / 4;                 // 4,194,304
  cvt_bf16_kernel<<<n4 / 256, 256, 0, stream>>>(x, xbf, n4);

  hipFuncSetAttribute((const void*)lstm_kernel,
                      hipFuncAttributeMaxDynamicSharedMemorySize, 65536);

  void* args[] = { (void*)&wih0, (void*)&whh0, (void*)&bih0, (void*)&bhh0,
                   (void*)&wih1, (void*)&whh1, (void*)&bih1, (void*)&bhh1,
                   (void*)&wfc,  (void*)&bfc,
                   (void*)&xbf,  (void*)&h0,   (void*)&h1,
                   (void*)&outp, (void*)&syncp, (void*)&hist };
  hipLaunchCooperativeKernel((void*)lstm_kernel, dim3(NWG), dim3(WGS),
                             args, 65536, stream);
}